// Round 11
// baseline (128.159 us; speedup 1.0000x reference)
//
#include <hip/hip_runtime.h>
#include <math.h>

// CRF loss: B=256, L=256, T=50.
// R11: chunked matrix-product scan — serial depth 255 -> 32.
//   normalizer = v0 . M1..M255 . 1,  M_l = mask_l ? E2*diag(eh_l) : I.
//   Scan kernel, 2048 blocks (1 wave each):
//     blocks 0..255    fwd vector chain:  u = v0 . M1..M31       (R10-proven)
//     blocks 256..511  bwd vector chain:  w = M224..M255 . 1     (R10-proven)
//     blocks 512..2047 middle chunks c=1..6: T_c = P_c^T, P_c = M_{32c}..M_{32c+31}
//       via T <- diag(eh_l)*E2^T*T : A-frags (E2^T) CONSTANT, and a K-permutation
//       sigma(c,q,j) = 32c+16(j>>2)+4q+2((j>>1)&1)+(j&1) makes the C/D-layout
//       output repack into the next B-frags LANE-LOCALLY (zero cross-lane ops).
//       32 packs + 32 independent MFMAs + row-scale per step; renorm by T[0][0].
//   Combine kernel (256 blocks): x=u; x <- T_c*x (6 serial matvecs); out =
//       ln2*(Sf+sum Sc+Scomb+Sb+log2(dot(x,w))) - gold.

#define TAGS 50
#define LEN 256
#define NB 256
#define VST 32            // vector chunk steps
#define NCH 6             // middle chunks
#define CST 32            // steps per middle chunk
#define INV_LN2 1.4426950408889634f
#define LN2 0.6931471805599453f

typedef __attribute__((ext_vector_type(8))) short bf16x8;
typedef __attribute__((ext_vector_type(4))) float f32x4;

#if __has_builtin(__builtin_amdgcn_exp2f)
#define EXP2F(x) __builtin_amdgcn_exp2f(x)
#else
#define EXP2F(x) exp2f(x)
#endif
#if __has_builtin(__builtin_amdgcn_logf)
#define LOG2F(x) __builtin_amdgcn_logf(x)
#else
#define LOG2F(x) log2f(x)
#endif
#if __has_builtin(__builtin_amdgcn_rcpf)
#define RCPF(x) __builtin_amdgcn_rcpf(x)
#else
#define RCPF(x) (1.0f / (x))
#endif

__device__ __forceinline__ float readlane_f(float v, int srclane) {
  return __builtin_bit_cast(float,
      __builtin_amdgcn_readlane(__builtin_bit_cast(int, v), srclane));
}

// Pack two fp32 -> (bf16(hi)<<16)|bf16(lo), round-half-up.
__device__ __forceinline__ int bfpack(float lo, float hi) {
  unsigned lb = __builtin_bit_cast(unsigned, lo) + 0x8000u;
  unsigned hb = __builtin_bit_cast(unsigned, hi) + 0x8000u;
#if __has_builtin(__builtin_amdgcn_perm)
  return (int)__builtin_amdgcn_perm(hb, lb, 0x07060302u);
#else
  return (int)((hb & 0xFFFF0000u) | (lb >> 16));
#endif
}

union U8 { int i[4]; bf16x8 v; };

// ws layout (floats)
#define WS_U(b)    ((b) * 64)
#define WS_W(b)    ((NB + (b)) * 64)
#define WS_SF(b)   (2 * NB * 64 + (b))
#define WS_SB(b)   (2 * NB * 64 + NB + (b))
#define WS_SC(b,c) (2 * NB * 64 + 2 * NB + (b) * NCH + (c))
#define WS_T(b,c)  (2 * NB * 64 + 2 * NB + NB * NCH + (((b) * NCH + (c)) * 64) * 64)

__global__ __launch_bounds__(64) void crf_scan_kernel(
    const float* __restrict__ feats,   // (B, L, T)
    const float* __restrict__ trans,   // (T, T)
    const int*   __restrict__ mask,    // (B, L)
    float*       __restrict__ ws)
{
  const int bid  = blockIdx.x;
  const int lane = threadIdx.x;
  const int q    = lane >> 4;
  const int n    = lane & 15;
  const f32x4 zero4 = {0.0f, 0.0f, 0.0f, 0.0f};

  if (bid < 2 * NB) {
    // ================= VECTOR CHAINS (R10-proven machinery) =================
    const bool is_fwd = bid < NB;
    const int b = is_fwd ? bid : bid - NB;

    __shared__ __align__(16) float fl[VST * TAGS];
    __shared__ int ml[VST];

    const int base_l = is_fwd ? 0 : (LEN - VST);      // fwd rows 0..31, bwd 224..255
    const float* fb = feats + ((size_t)b * LEN + base_l) * TAGS;
    const int*   mb = mask + b * LEN + base_l;

    {
      const float4* fv = (const float4*)fb;           // 400 float4, 16B-aligned
      for (int i = lane; i < (VST * TAGS) / 4; i += 64) {
        float4 v4 = fv[i];
        v4.x *= INV_LN2; v4.y *= INV_LN2; v4.z *= INV_LN2; v4.w *= INV_LN2;
        *(float4*)&fl[i * 4] = v4;
      }
      for (int i = lane; i < VST; i += 64) ml[i] = mb[i];
    }

    int tcl[4], vld[4];
#pragma unroll
    for (int t = 0; t < 4; ++t) {
      const int tg = n + 16 * t;
      vld[t] = tg < TAGS;
      tcl[t] = vld[t] ? tg : (TAGS - 1);
    }

    // B-frags, R8 K-permutation (fwd: E2[tagK][col]; bwd transposed).
    U8 Bfr[4][2];
#pragma unroll
    for (int t = 0; t < 4; ++t)
#pragma unroll
      for (int c = 0; c < 2; ++c)
#pragma unroll
        for (int r = 0; r < 4; ++r) {
          const int col = 16 * t + n;
          const int tag0 = 16 * c + 4 * q + r;
          const int tag1 = tag0 + 32;
          float e0 = 0.0f, e1 = 0.0f;
          if (col < TAGS) {
            if (tag0 < TAGS)
              e0 = EXP2F((is_fwd ? trans[tag0 * TAGS + col]
                                 : trans[col * TAGS + tag0]) * INV_LN2);
            if (tag1 < TAGS)
              e1 = EXP2F((is_fwd ? trans[tag1 * TAGS + col]
                                 : trans[col * TAGS + tag1]) * INV_LN2);
          }
          Bfr[t][c].i[r] = bfpack(e0, e1);
        }

    int addr[4];
#pragma unroll
    for (int r = 0; r < 4; ++r) addr[r] = (4 * q + r) * 4;

    __syncthreads();

    float v[4], S;
    if (is_fwd) {
      const float c0 = fl[0];
#pragma unroll
      for (int t = 0; t < 4; ++t) v[t] = vld[t] ? EXP2F(fl[tcl[t]] - c0) : 0.0f;
      S = c0;
      float eh[4];
#pragma unroll
      for (int t = 0; t < 4; ++t) eh[t] = EXP2F(fl[TAGS + tcl[t]]);
      int m_nxt = ml[1];

      for (int l = 1; l < VST; ++l) {
        const int m_cur = m_nxt;
        const int ln = (l + 1 < VST) ? (l + 1) : (VST - 1);
        const int P0 = bfpack(v[0], v[2]);
        const int P1 = bfpack(v[1], v[3]);
        const float cc = readlane_f(v[0], 0);
        const float rr = RCPF(cc);
        U8 A0, A1;
#pragma unroll
        for (int r = 0; r < 4; ++r) {
          A0.i[r] = __builtin_amdgcn_ds_bpermute(addr[r], P0);
          A1.i[r] = __builtin_amdgcn_ds_bpermute(addr[r], P1);
        }
        f32x4 d0 = __builtin_amdgcn_mfma_f32_16x16x32_bf16(A0.v, Bfr[0][0].v, zero4, 0, 0, 0);
        f32x4 d1 = __builtin_amdgcn_mfma_f32_16x16x32_bf16(A0.v, Bfr[1][0].v, zero4, 0, 0, 0);
        f32x4 d2 = __builtin_amdgcn_mfma_f32_16x16x32_bf16(A0.v, Bfr[2][0].v, zero4, 0, 0, 0);
        f32x4 d3 = __builtin_amdgcn_mfma_f32_16x16x32_bf16(A0.v, Bfr[3][0].v, zero4, 0, 0, 0);
        f32x4 g0 = __builtin_amdgcn_mfma_f32_16x16x32_bf16(A1.v, Bfr[0][1].v, zero4, 0, 0, 0);
        f32x4 g1 = __builtin_amdgcn_mfma_f32_16x16x32_bf16(A1.v, Bfr[1][1].v, zero4, 0, 0, 0);
        f32x4 g2 = __builtin_amdgcn_mfma_f32_16x16x32_bf16(A1.v, Bfr[2][1].v, zero4, 0, 0, 0);
        f32x4 g3 = __builtin_amdgcn_mfma_f32_16x16x32_bf16(A1.v, Bfr[3][1].v, zero4, 0, 0, 0);
        float ehn[4];
#pragma unroll
        for (int t = 0; t < 4; ++t) ehn[t] = fl[ln * TAGS + tcl[t]];
        const int m_n2 = ml[ln];
        v[0] = ((m_cur > 0) ? (d0[0] + g0[0]) * eh[0] : v[0]) * rr;
        v[1] = ((m_cur > 0) ? (d1[0] + g1[0]) * eh[1] : v[1]) * rr;
        v[2] = ((m_cur > 0) ? (d2[0] + g2[0]) * eh[2] : v[2]) * rr;
        v[3] = ((m_cur > 0) ? (d3[0] + g3[0]) * eh[3] : v[3]) * rr;
        S += LOG2F(cc);
#pragma unroll
        for (int t = 0; t < 4; ++t) eh[t] = EXP2F(ehn[t]);
        m_nxt = m_n2;
      }
      if (lane < 16) {
#pragma unroll
        for (int t = 0; t < 4; ++t) ws[WS_U(b) + n + 16 * t] = v[t];
      }
      if (lane == 0) ws[WS_SF(b)] = S;
    } else {
#pragma unroll
      for (int t = 0; t < 4; ++t) v[t] = vld[t] ? 1.0f : 0.0f;
      S = 0.0f;
      float eh[4];
#pragma unroll
      for (int t = 0; t < 4; ++t) eh[t] = EXP2F(fl[(VST - 1) * TAGS + tcl[t]]);
      int m_nxt = ml[VST - 1];

      for (int l = VST - 1; l >= 0; --l) {
        const int m_cur = m_nxt;
        const int ln = (l > 0) ? (l - 1) : 0;
        const float x0 = v[0] * eh[0];
        const float x1 = v[1] * eh[1];
        const float x2 = v[2] * eh[2];
        const float x3 = v[3] * eh[3];
        const int P0 = bfpack(x0, x2);
        const int P1 = bfpack(x1, x3);
        const float cc = readlane_f(v[0], 0);
        const float rr = RCPF(cc);
        U8 A0, A1;
#pragma unroll
        for (int r = 0; r < 4; ++r) {
          A0.i[r] = __builtin_amdgcn_ds_bpermute(addr[r], P0);
          A1.i[r] = __builtin_amdgcn_ds_bpermute(addr[r], P1);
        }
        f32x4 d0 = __builtin_amdgcn_mfma_f32_16x16x32_bf16(A0.v, Bfr[0][0].v, zero4, 0, 0, 0);
        f32x4 d1 = __builtin_amdgcn_mfma_f32_16x16x32_bf16(A0.v, Bfr[1][0].v, zero4, 0, 0, 0);
        f32x4 d2 = __builtin_amdgcn_mfma_f32_16x16x32_bf16(A0.v, Bfr[2][0].v, zero4, 0, 0, 0);
        f32x4 d3 = __builtin_amdgcn_mfma_f32_16x16x32_bf16(A0.v, Bfr[3][0].v, zero4, 0, 0, 0);
        f32x4 g0 = __builtin_amdgcn_mfma_f32_16x16x32_bf16(A1.v, Bfr[0][1].v, zero4, 0, 0, 0);
        f32x4 g1 = __builtin_amdgcn_mfma_f32_16x16x32_bf16(A1.v, Bfr[1][1].v, zero4, 0, 0, 0);
        f32x4 g2 = __builtin_amdgcn_mfma_f32_16x16x32_bf16(A1.v, Bfr[2][1].v, zero4, 0, 0, 0);
        f32x4 g3 = __builtin_amdgcn_mfma_f32_16x16x32_bf16(A1.v, Bfr[3][1].v, zero4, 0, 0, 0);
        float ehn[4];
#pragma unroll
        for (int t = 0; t < 4; ++t) ehn[t] = fl[ln * TAGS + tcl[t]];
        const int m_n2 = ml[ln];
        v[0] = ((m_cur > 0) ? (d0[0] + g0[0]) : v[0]) * rr;
        v[1] = ((m_cur > 0) ? (d1[0] + g1[0]) : v[1]) * rr;
        v[2] = ((m_cur > 0) ? (d2[0] + g2[0]) : v[2]) * rr;
        v[3] = ((m_cur > 0) ? (d3[0] + g3[0]) : v[3]) * rr;
        S += LOG2F(cc);
#pragma unroll
        for (int t = 0; t < 4; ++t) eh[t] = EXP2F(ehn[t]);
        m_nxt = m_n2;
      }
      if (lane < 16) {
#pragma unroll
        for (int t = 0; t < 4; ++t) ws[WS_W(b) + n + 16 * t] = v[t];
      }
      if (lane == 0) ws[WS_SB(b)] = S;
    }
    return;
  }

  // ======================= MIDDLE MATRIX CHUNKS =========================
  {
    const int i2 = bid - 2 * NB;
    const int b = i2 / NCH;
    const int cidx = i2 - b * NCH;                    // 0..5 -> chunk c = cidx+1
    const int l0 = CST * (cidx + 1);                  // global steps l0..l0+31

    __shared__ __align__(16) float em[CST * 52 + 16]; // emits*INV_LN2, stride 52
    __shared__ int ml[CST];

    // zero-init (pads must be exp2(0)=1-safe, never NaN)
    for (int i = lane; i < CST * 52 + 16; i += 64) em[i] = 0.0f;
    __syncthreads();

    const float* fbc = feats + ((size_t)b * LEN + l0) * TAGS;
    {
      const float4* fv = (const float4*)fbc;          // aligned: l0*50*4 % 16 == 0
      for (int i = lane; i < (CST * TAGS) / 4; i += 64) {
        const float4 v4 = fv[i];
        const int g = i * 4;
#pragma unroll
        for (int e = 0; e < 4; ++e) {
          const int gg = g + e;
          const int row = gg / TAGS;
          const int col = gg - row * TAGS;
          const float val = (e == 0) ? v4.x : (e == 1) ? v4.y : (e == 2) ? v4.z : v4.w;
          em[row * 52 + col] = val * INV_LN2;
        }
      }
      for (int i = lane; i < CST; i += 64) ml[i] = mask[b * LEN + l0 + i];
    }

    // Constant A-frags: E2^T with K-permutation sigma.
    // slot (c2,q,j): row k = 32c2 + 16*(j>>2) + 4q + 2*((j>>1)&1) + (j&1)
    U8 Afr[4][2];
#pragma unroll
    for (int tm = 0; tm < 4; ++tm)
#pragma unroll
      for (int c2 = 0; c2 < 2; ++c2)
#pragma unroll
        for (int rr = 0; rr < 4; ++rr) {
          const int m = 16 * tm + n;
          const int kr = 32 * c2 + 16 * (rr >> 1) + 4 * q + 2 * (rr & 1);
          const float e0 = (m < TAGS && kr < TAGS)
              ? EXP2F(trans[kr * TAGS + m] * INV_LN2) : 0.0f;
          const float e1 = (m < TAGS && kr + 1 < TAGS)
              ? EXP2F(trans[(kr + 1) * TAGS + m] * INV_LN2) : 0.0f;
          Afr[tm][c2].i[rr] = bfpack(e0, e1);
        }

    __syncthreads();

    // T = I in C-layout: d[tm][tn][e] = T[16tm+4q+e][16tn+n]
    f32x4 d[4][4];
#pragma unroll
    for (int tm = 0; tm < 4; ++tm)
#pragma unroll
      for (int tn = 0; tn < 4; ++tn)
#pragma unroll
        for (int e = 0; e < 4; ++e)
          d[tm][tn][e] = (tm == tn && n == 4 * q + e) ? 1.0f : 0.0f;

    float S = 0.0f;

    for (int l = 0; l < CST; ++l) {
      if (ml[l] > 0) {
        const float cc = readlane_f(d[0][0][0], 0);   // T[0][0] > 0
        const float rv = RCPF(cc);

        // Lane-local repack C-layout -> next B-frags (the sigma trick).
        U8 Bf[2][4];
#pragma unroll
        for (int c2 = 0; c2 < 2; ++c2)
#pragma unroll
          for (int tn = 0; tn < 4; ++tn) {
            Bf[c2][tn].i[0] = bfpack(d[2 * c2][tn][0], d[2 * c2][tn][1]);
            Bf[c2][tn].i[1] = bfpack(d[2 * c2][tn][2], d[2 * c2][tn][3]);
            Bf[c2][tn].i[2] = bfpack(d[2 * c2 + 1][tn][0], d[2 * c2 + 1][tn][1]);
            Bf[c2][tn].i[3] = bfpack(d[2 * c2 + 1][tn][2], d[2 * c2 + 1][tn][3]);
          }

        // Row scales: sc[tm][e] = exp2(emit[l][16tm+4q+e]) * rv
        float sc[4][4];
#pragma unroll
        for (int tm = 0; tm < 4; ++tm) {
          const f32x4 er = *(const f32x4*)&em[l * 52 + 16 * tm + 4 * q];
#pragma unroll
          for (int e = 0; e < 4; ++e) sc[tm][e] = EXP2F(er[e]) * rv;
        }

        // 32 MFMAs: D = A(c2=0)·B0 + A(c2=1)·B1 per (tm,tn); then scale.
#pragma unroll
        for (int tm = 0; tm < 4; ++tm)
#pragma unroll
          for (int tn = 0; tn < 4; ++tn) {
            f32x4 acc = __builtin_amdgcn_mfma_f32_16x16x32_bf16(
                Afr[tm][0].v, Bf[0][tn].v, zero4, 0, 0, 0);
            acc = __builtin_amdgcn_mfma_f32_16x16x32_bf16(
                Afr[tm][1].v, Bf[1][tn].v, acc, 0, 0, 0);
#pragma unroll
            for (int e = 0; e < 4; ++e) d[tm][tn][e] = acc[e] * sc[tm][e];
          }
        S += LOG2F(cc);
      }
    }

    // Store T (C-layout order) and S.
    float* tw = ws + WS_T(b, cidx) + lane * 64;
#pragma unroll
    for (int tm = 0; tm < 4; ++tm)
#pragma unroll
      for (int tn = 0; tn < 4; ++tn)
        *(f32x4*)&tw[(tm * 4 + tn) * 4] = d[tm][tn];
    if (lane == 0) ws[WS_SC(b, cidx)] = S;
  }
}

__global__ __launch_bounds__(64) void crf_combine_kernel(
    const float* __restrict__ feats,   // (B, L, T)
    const float* __restrict__ trans,   // (T, T)
    const int*   __restrict__ tags,    // (B, L)
    const int*   __restrict__ mask,    // (B, L)
    const float* __restrict__ ws,
    float*       __restrict__ out)     // (B,)
{
  const int b = blockIdx.x;
  const int lane = threadIdx.x;

  float x = ws[WS_U(b) + lane];                       // pads 0
  float Ssum = 0.0f;

  // x <- T_c * x, 6 serial matvecs. Row j=lane of T_c lives at:
  //   srcLane = 16*((j&15)>>2) + (i&15), tile = (j>>4)*4 + (i>>4), reg = j&3
  const int rbase = ((lane & 15) >> 2) * 16 * 64 + (lane >> 4) * 16 + (lane & 3);
  for (int c = 0; c < NCH; ++c) {
    const float* Tb = ws + WS_T(b, c) + rbase;
    float a0 = 0.0f, a1 = 0.0f, a2 = 0.0f, a3 = 0.0f;
#pragma unroll
    for (int i = 0; i < 64; i += 4) {
      a0 = fmaf(Tb[((i + 0) & 15) * 64 + ((i + 0) >> 4) * 4], readlane_f(x, i + 0), a0);
      a1 = fmaf(Tb[((i + 1) & 15) * 64 + ((i + 1) >> 4) * 4], readlane_f(x, i + 1), a1);
      a2 = fmaf(Tb[((i + 2) & 15) * 64 + ((i + 2) >> 4) * 4], readlane_f(x, i + 2), a2);
      a3 = fmaf(Tb[((i + 3) & 15) * 64 + ((i + 3) >> 4) * 4], readlane_f(x, i + 3), a3);
    }
    const float acc = (a0 + a1) + (a2 + a3);
    const float cc = readlane_f(acc, 0);              // > 0
    x = acc * RCPF(cc);
    Ssum += LOG2F(cc) + ws[WS_SC(b, c)];
  }

  // dot with w
  float s = x * ws[WS_W(b) + lane];
#pragma unroll
  for (int off = 32; off; off >>= 1) s += __shfl_xor(s, off, 64);

  // gold score
  const float* fb = feats + (size_t)b * (LEN * TAGS);
  const int*   tb = tags + b * LEN;
  const int*   mb = mask + b * LEN;
  float gp = 0.0f;
#pragma unroll
  for (int k = 0; k < 4; ++k) {
    const int p = lane + 64 * k;
    const int tg = tb[p];
    if (mb[p] > 0) {
      float vv = fb[p * TAGS + tg];
      if (p >= 1) vv += trans[tb[p - 1] * TAGS + tg];
      gp += vv;
    }
  }
#pragma unroll
  for (int off = 32; off; off >>= 1) gp += __shfl_xor(gp, off, 64);

  if (lane == 0) {
    const float Sf = ws[WS_SF(b)];
    const float Sb = ws[WS_SB(b)];
    out[b] = LN2 * (Sf + Sb + Ssum + LOG2F(s)) - gp;
  }
}

extern "C" void kernel_launch(void* const* d_in, const int* in_sizes, int n_in,
                              void* d_out, int out_size, void* d_ws, size_t ws_size,
                              hipStream_t stream) {
  const float* feats = (const float*)d_in[0];
  const float* trans = (const float*)d_in[1];
  const int*   tags  = (const int*)d_in[2];
  const int*   mask  = (const int*)d_in[3];
  float* out = (float*)d_out;
  float* ws  = (float*)d_ws;   // needs ~25.3 MB

  crf_scan_kernel<<<2 * NB + NB * NCH, 64, 0, stream>>>(feats, trans, mask, ws);
  crf_combine_kernel<<<NB, 64, 0, stream>>>(feats, trans, tags, mask, ws, out);
}

// Round 12
// 126.763 us; speedup vs baseline: 1.0110x; 1.0110x over previous
//
#include <hip/hip_runtime.h>
#include <math.h>

// CRF loss: B=256, L=256, T=50.
// R12 = R11 (chunked matrix-product scan, serial depth 255 -> 32) with:
//   1. __launch_bounds__(64,1) on the scan kernel: the R11 binary allocated only
//      80 VGPRs (default occupancy target) and spilled the 64-reg accumulator
//      tile + frags to scratch -> ~4k cyc/step. One wave/block needs no cap.
//   2. T stored COLUMN-MAJOR (T[j][i] at i*64+j) so combine's loads coalesce;
//      combine = 6 x (64 coalesced loads + readlane/FMA dot), ~2 us.
// Structure (verified R11, absmax 8.0):
//   blocks 0..255    fwd vector chain  u = v0 . M1..M31      (R10-proven)
//   blocks 256..511  bwd vector chain  w = M224..M255 . 1    (R10-proven)
//   blocks 512..2047 middle chunks c=1..6:  T <- diag(eh)*E2^T*T, 32 steps,
//     constant A-frags (E2^T) with sigma K-permutation making the C-layout ->
//     B-frag repack lane-local; renorm by T[0][0]; 32 MFMAs/step.

#define TAGS 50
#define LEN 256
#define NB 256
#define VST 32
#define NCH 6
#define CST 32
#define INV_LN2 1.4426950408889634f
#define LN2 0.6931471805599453f

typedef __attribute__((ext_vector_type(8))) short bf16x8;
typedef __attribute__((ext_vector_type(4))) float f32x4;

#if __has_builtin(__builtin_amdgcn_exp2f)
#define EXP2F(x) __builtin_amdgcn_exp2f(x)
#else
#define EXP2F(x) exp2f(x)
#endif
#if __has_builtin(__builtin_amdgcn_logf)
#define LOG2F(x) __builtin_amdgcn_logf(x)
#else
#define LOG2F(x) log2f(x)
#endif
#if __has_builtin(__builtin_amdgcn_rcpf)
#define RCPF(x) __builtin_amdgcn_rcpf(x)
#else
#define RCPF(x) (1.0f / (x))
#endif

__device__ __forceinline__ float readlane_f(float v, int srclane) {
  return __builtin_bit_cast(float,
      __builtin_amdgcn_readlane(__builtin_bit_cast(int, v), srclane));
}

__device__ __forceinline__ int bfpack(float lo, float hi) {
  unsigned lb = __builtin_bit_cast(unsigned, lo) + 0x8000u;
  unsigned hb = __builtin_bit_cast(unsigned, hi) + 0x8000u;
#if __has_builtin(__builtin_amdgcn_perm)
  return (int)__builtin_amdgcn_perm(hb, lb, 0x07060302u);
#else
  return (int)((hb & 0xFFFF0000u) | (lb >> 16));
#endif
}

union U8 { int i[4]; bf16x8 v; };

// ws layout (floats)
#define WS_U(b)    ((b) * 64)
#define WS_W(b)    ((NB + (b)) * 64)
#define WS_SF(b)   (2 * NB * 64 + (b))
#define WS_SB(b)   (2 * NB * 64 + NB + (b))
#define WS_SC(b,c) (2 * NB * 64 + 2 * NB + (b) * NCH + (c))
#define WS_T(b,c)  (2 * NB * 64 + 2 * NB + NB * NCH + (((b) * NCH + (c)) * 64) * 64)

__global__ __launch_bounds__(64, 1) void crf_scan_kernel(
    const float* __restrict__ feats,   // (B, L, T)
    const float* __restrict__ trans,   // (T, T)
    const int*   __restrict__ mask,    // (B, L)
    float*       __restrict__ ws)
{
  const int bid  = blockIdx.x;
  const int lane = threadIdx.x;
  const int q    = lane >> 4;
  const int n    = lane & 15;
  const f32x4 zero4 = {0.0f, 0.0f, 0.0f, 0.0f};

  if (bid < 2 * NB) {
    // ================= VECTOR CHAINS (R10-proven machinery) =================
    const bool is_fwd = bid < NB;
    const int b = is_fwd ? bid : bid - NB;

    __shared__ __align__(16) float fl[VST * TAGS];
    __shared__ int ml[VST];

    const int base_l = is_fwd ? 0 : (LEN - VST);
    const float* fb = feats + ((size_t)b * LEN + base_l) * TAGS;
    const int*   mb = mask + b * LEN + base_l;

    {
      const float4* fv = (const float4*)fb;
      for (int i = lane; i < (VST * TAGS) / 4; i += 64) {
        float4 v4 = fv[i];
        v4.x *= INV_LN2; v4.y *= INV_LN2; v4.z *= INV_LN2; v4.w *= INV_LN2;
        *(float4*)&fl[i * 4] = v4;
      }
      for (int i = lane; i < VST; i += 64) ml[i] = mb[i];
    }

    int tcl[4], vld[4];
#pragma unroll
    for (int t = 0; t < 4; ++t) {
      const int tg = n + 16 * t;
      vld[t] = tg < TAGS;
      tcl[t] = vld[t] ? tg : (TAGS - 1);
    }

    U8 Bfr[4][2];
#pragma unroll
    for (int t = 0; t < 4; ++t)
#pragma unroll
      for (int c = 0; c < 2; ++c)
#pragma unroll
        for (int r = 0; r < 4; ++r) {
          const int col = 16 * t + n;
          const int tag0 = 16 * c + 4 * q + r;
          const int tag1 = tag0 + 32;
          float e0 = 0.0f, e1 = 0.0f;
          if (col < TAGS) {
            if (tag0 < TAGS)
              e0 = EXP2F((is_fwd ? trans[tag0 * TAGS + col]
                                 : trans[col * TAGS + tag0]) * INV_LN2);
            if (tag1 < TAGS)
              e1 = EXP2F((is_fwd ? trans[tag1 * TAGS + col]
                                 : trans[col * TAGS + tag1]) * INV_LN2);
          }
          Bfr[t][c].i[r] = bfpack(e0, e1);
        }

    int addr[4];
#pragma unroll
    for (int r = 0; r < 4; ++r) addr[r] = (4 * q + r) * 4;

    __syncthreads();

    float v[4], S;
    if (is_fwd) {
      const float c0 = fl[0];
#pragma unroll
      for (int t = 0; t < 4; ++t) v[t] = vld[t] ? EXP2F(fl[tcl[t]] - c0) : 0.0f;
      S = c0;
      float eh[4];
#pragma unroll
      for (int t = 0; t < 4; ++t) eh[t] = EXP2F(fl[TAGS + tcl[t]]);
      int m_nxt = ml[1];

      for (int l = 1; l < VST; ++l) {
        const int m_cur = m_nxt;
        const int ln = (l + 1 < VST) ? (l + 1) : (VST - 1);
        const int P0 = bfpack(v[0], v[2]);
        const int P1 = bfpack(v[1], v[3]);
        const float cc = readlane_f(v[0], 0);
        const float rr = RCPF(cc);
        U8 A0, A1;
#pragma unroll
        for (int r = 0; r < 4; ++r) {
          A0.i[r] = __builtin_amdgcn_ds_bpermute(addr[r], P0);
          A1.i[r] = __builtin_amdgcn_ds_bpermute(addr[r], P1);
        }
        f32x4 d0 = __builtin_amdgcn_mfma_f32_16x16x32_bf16(A0.v, Bfr[0][0].v, zero4, 0, 0, 0);
        f32x4 d1 = __builtin_amdgcn_mfma_f32_16x16x32_bf16(A0.v, Bfr[1][0].v, zero4, 0, 0, 0);
        f32x4 d2 = __builtin_amdgcn_mfma_f32_16x16x32_bf16(A0.v, Bfr[2][0].v, zero4, 0, 0, 0);
        f32x4 d3 = __builtin_amdgcn_mfma_f32_16x16x32_bf16(A0.v, Bfr[3][0].v, zero4, 0, 0, 0);
        f32x4 g0 = __builtin_amdgcn_mfma_f32_16x16x32_bf16(A1.v, Bfr[0][1].v, zero4, 0, 0, 0);
        f32x4 g1 = __builtin_amdgcn_mfma_f32_16x16x32_bf16(A1.v, Bfr[1][1].v, zero4, 0, 0, 0);
        f32x4 g2 = __builtin_amdgcn_mfma_f32_16x16x32_bf16(A1.v, Bfr[2][1].v, zero4, 0, 0, 0);
        f32x4 g3 = __builtin_amdgcn_mfma_f32_16x16x32_bf16(A1.v, Bfr[3][1].v, zero4, 0, 0, 0);
        float ehn[4];
#pragma unroll
        for (int t = 0; t < 4; ++t) ehn[t] = fl[ln * TAGS + tcl[t]];
        const int m_n2 = ml[ln];
        v[0] = ((m_cur > 0) ? (d0[0] + g0[0]) * eh[0] : v[0]) * rr;
        v[1] = ((m_cur > 0) ? (d1[0] + g1[0]) * eh[1] : v[1]) * rr;
        v[2] = ((m_cur > 0) ? (d2[0] + g2[0]) * eh[2] : v[2]) * rr;
        v[3] = ((m_cur > 0) ? (d3[0] + g3[0]) * eh[3] : v[3]) * rr;
        S += LOG2F(cc);
#pragma unroll
        for (int t = 0; t < 4; ++t) eh[t] = EXP2F(ehn[t]);
        m_nxt = m_n2;
      }
      if (lane < 16) {
#pragma unroll
        for (int t = 0; t < 4; ++t) ws[WS_U(b) + n + 16 * t] = v[t];
      }
      if (lane == 0) ws[WS_SF(b)] = S;
    } else {
#pragma unroll
      for (int t = 0; t < 4; ++t) v[t] = vld[t] ? 1.0f : 0.0f;
      S = 0.0f;
      float eh[4];
#pragma unroll
      for (int t = 0; t < 4; ++t) eh[t] = EXP2F(fl[(VST - 1) * TAGS + tcl[t]]);
      int m_nxt = ml[VST - 1];

      for (int l = VST - 1; l >= 0; --l) {
        const int m_cur = m_nxt;
        const int ln = (l > 0) ? (l - 1) : 0;
        const float x0 = v[0] * eh[0];
        const float x1 = v[1] * eh[1];
        const float x2 = v[2] * eh[2];
        const float x3 = v[3] * eh[3];
        const int P0 = bfpack(x0, x2);
        const int P1 = bfpack(x1, x3);
        const float cc = readlane_f(v[0], 0);
        const float rr = RCPF(cc);
        U8 A0, A1;
#pragma unroll
        for (int r = 0; r < 4; ++r) {
          A0.i[r] = __builtin_amdgcn_ds_bpermute(addr[r], P0);
          A1.i[r] = __builtin_amdgcn_ds_bpermute(addr[r], P1);
        }
        f32x4 d0 = __builtin_amdgcn_mfma_f32_16x16x32_bf16(A0.v, Bfr[0][0].v, zero4, 0, 0, 0);
        f32x4 d1 = __builtin_amdgcn_mfma_f32_16x16x32_bf16(A0.v, Bfr[1][0].v, zero4, 0, 0, 0);
        f32x4 d2 = __builtin_amdgcn_mfma_f32_16x16x32_bf16(A0.v, Bfr[2][0].v, zero4, 0, 0, 0);
        f32x4 d3 = __builtin_amdgcn_mfma_f32_16x16x32_bf16(A0.v, Bfr[3][0].v, zero4, 0, 0, 0);
        f32x4 g0 = __builtin_amdgcn_mfma_f32_16x16x32_bf16(A1.v, Bfr[0][1].v, zero4, 0, 0, 0);
        f32x4 g1 = __builtin_amdgcn_mfma_f32_16x16x32_bf16(A1.v, Bfr[1][1].v, zero4, 0, 0, 0);
        f32x4 g2 = __builtin_amdgcn_mfma_f32_16x16x32_bf16(A1.v, Bfr[2][1].v, zero4, 0, 0, 0);
        f32x4 g3 = __builtin_amdgcn_mfma_f32_16x16x32_bf16(A1.v, Bfr[3][1].v, zero4, 0, 0, 0);
        float ehn[4];
#pragma unroll
        for (int t = 0; t < 4; ++t) ehn[t] = fl[ln * TAGS + tcl[t]];
        const int m_n2 = ml[ln];
        v[0] = ((m_cur > 0) ? (d0[0] + g0[0]) : v[0]) * rr;
        v[1] = ((m_cur > 0) ? (d1[0] + g1[0]) : v[1]) * rr;
        v[2] = ((m_cur > 0) ? (d2[0] + g2[0]) : v[2]) * rr;
        v[3] = ((m_cur > 0) ? (d3[0] + g3[0]) : v[3]) * rr;
        S += LOG2F(cc);
#pragma unroll
        for (int t = 0; t < 4; ++t) eh[t] = EXP2F(ehn[t]);
        m_nxt = m_n2;
      }
      if (lane < 16) {
#pragma unroll
        for (int t = 0; t < 4; ++t) ws[WS_W(b) + n + 16 * t] = v[t];
      }
      if (lane == 0) ws[WS_SB(b)] = S;
    }
    return;
  }

  // ======================= MIDDLE MATRIX CHUNKS =========================
  {
    const int i2 = bid - 2 * NB;
    const int b = i2 / NCH;
    const int cidx = i2 - b * NCH;                    // chunk c = cidx+1
    const int l0 = CST * (cidx + 1);

    __shared__ __align__(16) float em[CST * 52 + 16];
    __shared__ int ml[CST];

    for (int i = lane; i < CST * 52 + 16; i += 64) em[i] = 0.0f;
    __syncthreads();

    const float* fbc = feats + ((size_t)b * LEN + l0) * TAGS;
    {
      const float4* fv = (const float4*)fbc;
      for (int i = lane; i < (CST * TAGS) / 4; i += 64) {
        const float4 v4 = fv[i];
        const int g = i * 4;
#pragma unroll
        for (int e = 0; e < 4; ++e) {
          const int gg = g + e;
          const int row = gg / TAGS;
          const int col = gg - row * TAGS;
          const float val = (e == 0) ? v4.x : (e == 1) ? v4.y : (e == 2) ? v4.z : v4.w;
          em[row * 52 + col] = val * INV_LN2;
        }
      }
      for (int i = lane; i < CST; i += 64) ml[i] = mask[b * LEN + l0 + i];
    }

    // Constant A-frags: E2^T with sigma: slot (c2,q,j) -> row 32c2+16(j>>2)+4q+2((j>>1)&1)+(j&1)
    U8 Afr[4][2];
#pragma unroll
    for (int tm = 0; tm < 4; ++tm)
#pragma unroll
      for (int c2 = 0; c2 < 2; ++c2)
#pragma unroll
        for (int rr = 0; rr < 4; ++rr) {
          const int m = 16 * tm + n;
          const int kr = 32 * c2 + 16 * (rr >> 1) + 4 * q + 2 * (rr & 1);
          const float e0 = (m < TAGS && kr < TAGS)
              ? EXP2F(trans[kr * TAGS + m] * INV_LN2) : 0.0f;
          const float e1 = (m < TAGS && kr + 1 < TAGS)
              ? EXP2F(trans[(kr + 1) * TAGS + m] * INV_LN2) : 0.0f;
          Afr[tm][c2].i[rr] = bfpack(e0, e1);
        }

    __syncthreads();

    // T = I in C-layout: d[tm][tn][e] = T[16tm+4q+e][16tn+n]
    f32x4 d[4][4];
#pragma unroll
    for (int tm = 0; tm < 4; ++tm)
#pragma unroll
      for (int tn = 0; tn < 4; ++tn)
#pragma unroll
        for (int e = 0; e < 4; ++e)
          d[tm][tn][e] = (tm == tn && n == 4 * q + e) ? 1.0f : 0.0f;

    float S = 0.0f;

    for (int l = 0; l < CST; ++l) {
      if (ml[l] > 0) {
        const float cc = readlane_f(d[0][0][0], 0);   // T[0][0] > 0
        const float rv = RCPF(cc);

        U8 Bf[2][4];
#pragma unroll
        for (int c2 = 0; c2 < 2; ++c2)
#pragma unroll
          for (int tn = 0; tn < 4; ++tn) {
            Bf[c2][tn].i[0] = bfpack(d[2 * c2][tn][0], d[2 * c2][tn][1]);
            Bf[c2][tn].i[1] = bfpack(d[2 * c2][tn][2], d[2 * c2][tn][3]);
            Bf[c2][tn].i[2] = bfpack(d[2 * c2 + 1][tn][0], d[2 * c2 + 1][tn][1]);
            Bf[c2][tn].i[3] = bfpack(d[2 * c2 + 1][tn][2], d[2 * c2 + 1][tn][3]);
          }

        float sc[4][4];
#pragma unroll
        for (int tm = 0; tm < 4; ++tm) {
          const f32x4 er = *(const f32x4*)&em[l * 52 + 16 * tm + 4 * q];
#pragma unroll
          for (int e = 0; e < 4; ++e) sc[tm][e] = EXP2F(er[e]) * rv;
        }

#pragma unroll
        for (int tm = 0; tm < 4; ++tm)
#pragma unroll
          for (int tn = 0; tn < 4; ++tn) {
            f32x4 acc = __builtin_amdgcn_mfma_f32_16x16x32_bf16(
                Afr[tm][0].v, Bf[0][tn].v, zero4, 0, 0, 0);
            acc = __builtin_amdgcn_mfma_f32_16x16x32_bf16(
                Afr[tm][1].v, Bf[1][tn].v, acc, 0, 0, 0);
#pragma unroll
            for (int e = 0; e < 4; ++e) d[tm][tn][e] = acc[e] * sc[tm][e];
          }
        S += LOG2F(cc);
      }
    }

    // Store T COLUMN-MAJOR: T[row][colidx] at colidx*64 + row (coalesced combine).
    float* tw = ws + WS_T(b, cidx);
#pragma unroll
    for (int tm = 0; tm < 4; ++tm)
#pragma unroll
      for (int tn = 0; tn < 4; ++tn)
#pragma unroll
        for (int e = 0; e < 4; ++e)
          tw[(16 * tn + n) * 64 + 16 * tm + 4 * q + e] = d[tm][tn][e];
    if (lane == 0) ws[WS_SC(b, cidx)] = S;
  }
}

__global__ __launch_bounds__(64) void crf_combine_kernel(
    const float* __restrict__ feats,   // (B, L, T)
    const float* __restrict__ trans,   // (T, T)
    const int*   __restrict__ tags,    // (B, L)
    const int*   __restrict__ mask,    // (B, L)
    const float* __restrict__ ws,
    float*       __restrict__ out)     // (B,)
{
  const int b = blockIdx.x;
  const int lane = threadIdx.x;

  float x = ws[WS_U(b) + lane];                       // pads 0
  float Ssum = 0.0f;

  // x <- T_c * x: col-major T -> load T[lane][i] at i*64+lane (coalesced).
  for (int c = 0; c < NCH; ++c) {
    const float* Tb = ws + WS_T(b, c) + lane;
    float a0 = 0.0f, a1 = 0.0f, a2 = 0.0f, a3 = 0.0f;
#pragma unroll
    for (int i = 0; i < 64; i += 4) {
      a0 = fmaf(Tb[(i + 0) * 64], readlane_f(x, i + 0), a0);
      a1 = fmaf(Tb[(i + 1) * 64], readlane_f(x, i + 1), a1);
      a2 = fmaf(Tb[(i + 2) * 64], readlane_f(x, i + 2), a2);
      a3 = fmaf(Tb[(i + 3) * 64], readlane_f(x, i + 3), a3);
    }
    const float acc = (a0 + a1) + (a2 + a3);
    const float cc = readlane_f(acc, 0);              // > 0
    x = acc * RCPF(cc);
    Ssum += LOG2F(cc) + ws[WS_SC(b, c)];
  }

  // dot with w
  float s = x * ws[WS_W(b) + lane];
#pragma unroll
  for (int off = 32; off; off >>= 1) s += __shfl_xor(s, off, 64);

  // gold score
  const float* fb = feats + (size_t)b * (LEN * TAGS);
  const int*   tb = tags + b * LEN;
  const int*   mb = mask + b * LEN;
  float gp = 0.0f;
#pragma unroll
  for (int k = 0; k < 4; ++k) {
    const int p = lane + 64 * k;
    const int tg = tb[p];
    if (mb[p] > 0) {
      float vv = fb[p * TAGS + tg];
      if (p >= 1) vv += trans[tb[p - 1] * TAGS + tg];
      gp += vv;
    }
  }
#pragma unroll
  for (int off = 32; off; off >>= 1) gp += __shfl_xor(gp, off, 64);

  if (lane == 0) {
    const float Sf = ws[WS_SF(b)];
    const float Sb = ws[WS_SB(b)];
    out[b] = LN2 * (Sf + Sb + Ssum + LOG2F(s)) - gp;
  }
}

extern "C" void kernel_launch(void* const* d_in, const int* in_sizes, int n_in,
                              void* d_out, int out_size, void* d_ws, size_t ws_size,
                              hipStream_t stream) {
  const float* feats = (const float*)d_in[0];
  const float* trans = (const float*)d_in[1];
  const int*   tags  = (const int*)d_in[2];
  const int*   mask  = (const int*)d_in[3];
  float* out = (float*)d_out;
  float* ws  = (float*)d_ws;   // needs ~25.3 MB

  crf_scan_kernel<<<2 * NB + NB * NCH, 64, 0, stream>>>(feats, trans, mask, ws);
  crf_combine_kernel<<<NB, 64, 0, stream>>>(feats, trans, tags, mask, ws, out);
}